// Round 5
// baseline (479.731 us; speedup 1.0000x reference)
//
#include <hip/hip_runtime.h>

#define D 64
#define ALPHA 0.5f
#define FXSCALE 16777216.f   // 2^24 fixed-point quantum for degree accumulation

typedef unsigned long long u64;
typedef unsigned char u8;
typedef unsigned short u16;

// float -> bf16 (round to nearest even), as ushort
static __device__ __forceinline__ u16 f2bf(float f) {
    unsigned u = __float_as_uint(f);
    unsigned r = (u + 0x7fffu + ((u >> 16) & 1u)) >> 16;
    return (u16)r;
}
// bf16 (ushort) -> float: exact
static __device__ __forceinline__ float bf2f(u16 h) {
    return __uint_as_float(((unsigned)h) << 16);
}

__global__ void zero4_kernel(int4* __restrict__ p, int n4) {
    int i = blockIdx.x * blockDim.x + threadIdx.x;
    if (i < n4) p[i] = make_int4(0, 0, 0, 0);
}

// one packed 64-bit atomic per (edge, side): hi32 = count, lo32 = sum(w * 2^24).
// The returned old count IS this edge's rank within its destination segment.
__global__ void deg_hist_rank_kernel(const int* __restrict__ row, const int* __restrict__ col,
                                     const float* __restrict__ w,
                                     u64* __restrict__ pk,
                                     u8* __restrict__ rank_f, u8* __restrict__ rank_b,
                                     int N, int E) {
    int stride = gridDim.x * blockDim.x;
    for (int e = blockIdx.x * blockDim.x + threadIdx.x; e < E; e += stride) {
        int r = row[e], c = col[e];
        u64 v = (1ULL << 32) | (u64)__float2uint_rn(w[e] * FXSCALE);
        u64 o1 = atomicAdd(&pk[r], v);
        rank_f[e] = (u8)(o1 >> 32);
        u64 o2 = atomicAdd(&pk[N + c], v);
        rank_b[e] = (u8)(o2 >> 32);
    }
}

// dinv[i] = deg^-1/2 (0 if empty) from packed fixed-point sum
__global__ void unpack_kernel(const u64* __restrict__ pk, float* __restrict__ dinv, int L) {
    int i = blockIdx.x * blockDim.x + threadIdx.x;
    if (i < L) {
        float s = (float)(unsigned int)(pk[i] & 0xffffffffULL) * (1.f / FXSCALE);
        dinv[i] = (s > 0.f) ? rsqrtf(s) : 0.f;
    }
}

// ---- 3-kernel exclusive scan of counts (pk >> 32) -> ptr[0..L], blocks of 512 ----
__global__ void scan1_kernel(const u64* __restrict__ pk, int* __restrict__ bsum, int L) {
    __shared__ int s[512];
    int t = threadIdx.x;
    int i = blockIdx.x * 512 + t;
    s[t] = (i < L) ? (int)(pk[i] >> 32) : 0;
    __syncthreads();
    for (int off = 256; off; off >>= 1) {
        if (t < off) s[t] += s[t + off];
        __syncthreads();
    }
    if (t == 0) bsum[blockIdx.x] = s[0];
}

__global__ void scan2_kernel(int* __restrict__ bsum, int nb) {
    __shared__ int s[512];
    int t = threadIdx.x;
    int v = (t < nb) ? bsum[t] : 0;
    s[t] = v;
    __syncthreads();
    for (int off = 1; off < 512; off <<= 1) {
        int u = (t >= off) ? s[t - off] : 0;
        __syncthreads();
        s[t] += u;
        __syncthreads();
    }
    if (t < nb) bsum[t] = s[t] - v;   // exclusive block offsets
}

__global__ void scan3_kernel(const u64* __restrict__ pk, const int* __restrict__ bsum,
                             int* __restrict__ ptr, int L, int total) {
    __shared__ int s[512];
    int t = threadIdx.x;
    int i = blockIdx.x * 512 + t;
    int v = (i < L) ? (int)(pk[i] >> 32) : 0;
    s[t] = v;
    __syncthreads();
    for (int off = 1; off < 512; off <<= 1) {
        int u = (t >= off) ? s[t - off] : 0;
        __syncthreads();
        s[t] += u;
        __syncthreads();
    }
    if (i < L) ptr[i] = bsum[blockIdx.x] + s[t] - v;
    if (i == 0) ptr[L] = total;
}

// place each edge in both CSR segments at ptr[dst] + captured rank — NO atomics
__global__ void fill_ranked_kernel(const int* __restrict__ row, const int* __restrict__ col,
                                   const float* __restrict__ w,
                                   const float* __restrict__ dinv,
                                   const u8* __restrict__ rank_f, const u8* __restrict__ rank_b,
                                   const int* __restrict__ ptr,
                                   float2* __restrict__ edata,
                                   int N, int E) {
    int e = blockIdx.x * blockDim.x + threadIdx.x;
    if (e >= E) return;
    int r = row[e], c = col[e];
    float wn = w[e] * dinv[r] * dinv[N + c];
    int p1 = ptr[r] + rank_f[e];         // fwd: dst=r, src=c
    edata[p1] = make_float2(__int_as_float(c), wn);
    int p2 = ptr[N + c] + rank_b[e];     // bwd: dst=c, src=r
    edata[p2] = make_float2(__int_as_float(r), wn);
}

// fused: y1 = bf16(ALPHA * x @ Ws^T), y2 = bf16((1-ALPHA) * x @ Wd^T), one pass over x
__global__ void transform2_kernel(const float* __restrict__ x,
                                  const float* __restrict__ Ws, const float* __restrict__ Wd,
                                  u16* __restrict__ y1, u16* __restrict__ y2, int N) {
    __shared__ float xs[64][65];
    __shared__ float Wt1[64][68];
    __shared__ float Wt2[64][68];
    int t = threadIdx.x;
    for (int i = t; i < 4096; i += 256) {
        int o = i >> 6, k = i & 63;
        Wt1[k][o] = Ws[i];
        Wt2[k][o] = Wd[i];
    }
    int r0 = blockIdx.x * 64;
    for (int i = t; i < 4096; i += 256) {
        int r = i >> 6, k = i & 63;
        int gr = r0 + r;
        xs[r][k] = (gr < N) ? x[(size_t)gr * D + k] : 0.f;
    }
    __syncthreads();
    int ro = t >> 4, co = t & 15;
    float a1[4][4] = {}, a2[4][4] = {};
#pragma unroll 4
    for (int k = 0; k < 64; ++k) {
        float v0 = xs[ro * 4 + 0][k];
        float v1 = xs[ro * 4 + 1][k];
        float v2 = xs[ro * 4 + 2][k];
        float v3 = xs[ro * 4 + 3][k];
        float4 b1 = *(const float4*)&Wt1[k][co * 4];
        float4 b2 = *(const float4*)&Wt2[k][co * 4];
        a1[0][0] += v0 * b1.x; a1[0][1] += v0 * b1.y; a1[0][2] += v0 * b1.z; a1[0][3] += v0 * b1.w;
        a1[1][0] += v1 * b1.x; a1[1][1] += v1 * b1.y; a1[1][2] += v1 * b1.z; a1[1][3] += v1 * b1.w;
        a1[2][0] += v2 * b1.x; a1[2][1] += v2 * b1.y; a1[2][2] += v2 * b1.z; a1[2][3] += v2 * b1.w;
        a1[3][0] += v3 * b1.x; a1[3][1] += v3 * b1.y; a1[3][2] += v3 * b1.z; a1[3][3] += v3 * b1.w;
        a2[0][0] += v0 * b2.x; a2[0][1] += v0 * b2.y; a2[0][2] += v0 * b2.z; a2[0][3] += v0 * b2.w;
        a2[1][0] += v1 * b2.x; a2[1][1] += v1 * b2.y; a2[1][2] += v1 * b2.z; a2[1][3] += v1 * b2.w;
        a2[2][0] += v2 * b2.x; a2[2][1] += v2 * b2.y; a2[2][2] += v2 * b2.z; a2[2][3] += v2 * b2.w;
        a2[3][0] += v3 * b2.x; a2[3][1] += v3 * b2.y; a2[3][2] += v3 * b2.z; a2[3][3] += v3 * b2.w;
    }
#pragma unroll
    for (int i = 0; i < 4; ++i) {
        int gr = r0 + ro * 4 + i;
        if (gr < N) {
            ushort4 o1, o2;
            o1.x = f2bf(a1[i][0] * ALPHA); o1.y = f2bf(a1[i][1] * ALPHA);
            o1.z = f2bf(a1[i][2] * ALPHA); o1.w = f2bf(a1[i][3] * ALPHA);
            o2.x = f2bf(a2[i][0] * (1.f - ALPHA)); o2.y = f2bf(a2[i][1] * (1.f - ALPHA));
            o2.z = f2bf(a2[i][2] * (1.f - ALPHA)); o2.w = f2bf(a2[i][3] * (1.f - ALPHA));
            *(ushort4*)&y1[(size_t)gr * D + co * 4] = o1;
            *(ushort4*)&y2[(size_t)gr * D + co * 4] = o2;
        }
    }
}

// one wave per node: bias + fwd segment (y1) + bwd segment (y2), single nt out write
__global__ void gather_merged_kernel(const int* __restrict__ ptr, const float2* __restrict__ ed,
                                     const u16* __restrict__ y1, const u16* __restrict__ y2,
                                     const float* __restrict__ b_src, const float* __restrict__ b_dst,
                                     float* __restrict__ out, int N) {
    int lane = threadIdx.x & 63;
    int node = blockIdx.x * (blockDim.x >> 6) + (threadIdx.x >> 6);
    if (node >= N) return;
    float acc0 = ALPHA * b_src[lane] + (1.f - ALPHA) * b_dst[lane];
    float acc1 = 0.f;
    const u64* edq = (const u64*)ed;
    int e0 = ptr[node], e1 = ptr[node + 1];
    int e = e0;
    for (; e + 2 <= e1; e += 2) {
        u64 q0 = __builtin_nontemporal_load(&edq[e]);
        u64 q1 = __builtin_nontemporal_load(&edq[e + 1]);
        int s0 = (int)(q0 & 0xffffffffULL);
        int s1 = (int)(q1 & 0xffffffffULL);
        float w0 = __uint_as_float((unsigned)(q0 >> 32));
        float w1 = __uint_as_float((unsigned)(q1 >> 32));
        acc0 += w0 * bf2f(y1[(size_t)s0 * D + lane]);
        acc1 += w1 * bf2f(y1[(size_t)s1 * D + lane]);
    }
    if (e < e1) {
        u64 q0 = __builtin_nontemporal_load(&edq[e]);
        int s0 = (int)(q0 & 0xffffffffULL);
        float w0 = __uint_as_float((unsigned)(q0 >> 32));
        acc0 += w0 * bf2f(y1[(size_t)s0 * D + lane]);
    }
    e0 = ptr[N + node]; e1 = ptr[N + node + 1];
    for (e = e0; e + 2 <= e1; e += 2) {
        u64 q0 = __builtin_nontemporal_load(&edq[e]);
        u64 q1 = __builtin_nontemporal_load(&edq[e + 1]);
        int s0 = (int)(q0 & 0xffffffffULL);
        int s1 = (int)(q1 & 0xffffffffULL);
        float w0 = __uint_as_float((unsigned)(q0 >> 32));
        float w1 = __uint_as_float((unsigned)(q1 >> 32));
        acc0 += w0 * bf2f(y2[(size_t)s0 * D + lane]);
        acc1 += w1 * bf2f(y2[(size_t)s1 * D + lane]);
    }
    if (e < e1) {
        u64 q0 = __builtin_nontemporal_load(&edq[e]);
        int s0 = (int)(q0 & 0xffffffffULL);
        float w0 = __uint_as_float((unsigned)(q0 >> 32));
        acc0 += w0 * bf2f(y2[(size_t)s0 * D + lane]);
    }
    __builtin_nontemporal_store(acc0 + acc1, &out[(size_t)node * D + lane]);
}

extern "C" void kernel_launch(void* const* d_in, const int* in_sizes, int n_in,
                              void* d_out, int out_size, void* d_ws, size_t ws_size,
                              hipStream_t stream) {
    const float* x     = (const float*)d_in[0];
    const int*   ei    = (const int*)d_in[1];
    const float* w     = (const float*)d_in[2];
    const float* W_src = (const float*)d_in[3];
    const float* b_src = (const float*)d_in[4];
    const float* W_dst = (const float*)d_in[5];
    const float* b_dst = (const float*)d_in[6];
    float* out = (float*)d_out;

    const int N = in_sizes[0] / D;
    const int E = in_sizes[2];
    const int* row = ei;
    const int* col = ei + E;
    const int L = 2 * N;
    const int NB = (L + 511) / 512;    // 391 for N=100k, fits scan2's 512

    // workspace layout (16B-aligned chunks), ~57 MB total
    char* base = (char*)d_ws;
    size_t off = 0;
    auto take = [&](size_t bytes) { char* p = base + off; off = (off + bytes + 15) & ~(size_t)15; return p; };
    u64*    pk     = (u64*)take((size_t)L * 8);
    float*  dinv   = (float*)take((size_t)L * 4);
    int*    ptr    = (int*)take((size_t)(L + 1) * 4);
    int*    bsum   = (int*)take(512 * 4);
    u8*     rank_f = (u8*)take((size_t)E);
    u8*     rank_b = (u8*)take((size_t)E);
    u16*    y1     = (u16*)take((size_t)N * D * 2);
    u16*    y2     = (u16*)take((size_t)N * D * 2);
    float2* edata  = (float2*)take((size_t)2 * E * 8);

    // 1. zero packed degree/count array (2N u64 = N int4)
    zero4_kernel<<<(N + 255) / 256, 256, 0, stream>>>((int4*)pk, N);
    // 2. packed degrees + histogram, capturing per-edge ranks from atomic returns
    deg_hist_rank_kernel<<<2048, 256, 0, stream>>>(row, col, w, pk, rank_f, rank_b, N, E);
    // 3. d^-1/2
    unpack_kernel<<<(L + 255) / 256, 256, 0, stream>>>(pk, dinv, L);
    // 4. exclusive scan of counts -> ptr
    scan1_kernel<<<NB, 512, 0, stream>>>(pk, bsum, L);
    scan2_kernel<<<1, 512, 0, stream>>>(bsum, NB);
    scan3_kernel<<<NB, 512, 0, stream>>>(pk, bsum, ptr, L, 2 * E);
    // 5. fill CSR edge lists via ptr+rank (atomic-free)
    fill_ranked_kernel<<<(E + 255) / 256, 256, 0, stream>>>(row, col, w, dinv, rank_f, rank_b,
                                                            ptr, edata, N, E);
    // 6. both transforms in one pass (bf16 outputs), then one merged gather
    transform2_kernel<<<(N + 63) / 64, 256, 0, stream>>>(x, W_src, W_dst, y1, y2, N);
    gather_merged_kernel<<<(N + 3) / 4, 256, 0, stream>>>(ptr, edata, y1, y2,
                                                          b_src, b_dst, out, N);
}

// Round 7
// 366.821 us; speedup vs baseline: 1.3078x; 1.3078x over previous
//
#include <hip/hip_runtime.h>

#define D 64
#define ALPHA 0.5f
#define FXSCALE 16777216.f   // 2^24 fixed-point quantum for degree accumulation

typedef unsigned long long u64;
typedef unsigned char u8;
typedef unsigned short u16;
typedef float f32x4 __attribute__((ext_vector_type(4)));   // NT-store-compatible vector

// float -> bf16 (round to nearest even), as ushort
static __device__ __forceinline__ u16 f2bf(float f) {
    unsigned u = __float_as_uint(f);
    unsigned r = (u + 0x7fffu + ((u >> 16) & 1u)) >> 16;
    return (u16)r;
}
// bf16 (ushort) -> float: exact
static __device__ __forceinline__ float bf2f(u16 h) {
    return __uint_as_float(((unsigned)h) << 16);
}

__global__ void zero4_kernel(int4* __restrict__ p, int n4) {
    int i = blockIdx.x * blockDim.x + threadIdx.x;
    if (i < n4) p[i] = make_int4(0, 0, 0, 0);
}

// one packed 64-bit atomic per (edge, side): hi32 = count, lo32 = sum(w * 2^24).
// The returned old count IS this edge's rank within its destination segment.
__global__ void deg_hist_rank_kernel(const int* __restrict__ row, const int* __restrict__ col,
                                     const float* __restrict__ w,
                                     u64* __restrict__ pk,
                                     u8* __restrict__ rank_f, u8* __restrict__ rank_b,
                                     int N, int E) {
    int stride = gridDim.x * blockDim.x;
    for (int e = blockIdx.x * blockDim.x + threadIdx.x; e < E; e += stride) {
        int r = row[e], c = col[e];
        u64 v = (1ULL << 32) | (u64)__float2uint_rn(w[e] * FXSCALE);
        u64 o1 = atomicAdd(&pk[r], v);
        rank_f[e] = (u8)(o1 >> 32);
        u64 o2 = atomicAdd(&pk[N + c], v);
        rank_b[e] = (u8)(o2 >> 32);
    }
}

// dinv[i] = deg^-1/2 (0 if empty) from packed fixed-point sum
__global__ void unpack_kernel(const u64* __restrict__ pk, float* __restrict__ dinv, int L) {
    int i = blockIdx.x * blockDim.x + threadIdx.x;
    if (i < L) {
        float s = (float)(unsigned int)(pk[i] & 0xffffffffULL) * (1.f / FXSCALE);
        dinv[i] = (s > 0.f) ? rsqrtf(s) : 0.f;
    }
}

// ---- 3-kernel exclusive scan of counts (pk >> 32) -> ptr[0..L], blocks of 512 ----
__global__ void scan1_kernel(const u64* __restrict__ pk, int* __restrict__ bsum, int L) {
    __shared__ int s[512];
    int t = threadIdx.x;
    int i = blockIdx.x * 512 + t;
    s[t] = (i < L) ? (int)(pk[i] >> 32) : 0;
    __syncthreads();
    for (int off = 256; off; off >>= 1) {
        if (t < off) s[t] += s[t + off];
        __syncthreads();
    }
    if (t == 0) bsum[blockIdx.x] = s[0];
}

__global__ void scan2_kernel(int* __restrict__ bsum, int nb) {
    __shared__ int s[512];
    int t = threadIdx.x;
    int v = (t < nb) ? bsum[t] : 0;
    s[t] = v;
    __syncthreads();
    for (int off = 1; off < 512; off <<= 1) {
        int u = (t >= off) ? s[t - off] : 0;
        __syncthreads();
        s[t] += u;
        __syncthreads();
    }
    if (t < nb) bsum[t] = s[t] - v;   // exclusive block offsets
}

__global__ void scan3_kernel(const u64* __restrict__ pk, const int* __restrict__ bsum,
                             int* __restrict__ ptr, int L, int total) {
    __shared__ int s[512];
    int t = threadIdx.x;
    int i = blockIdx.x * 512 + t;
    int v = (i < L) ? (int)(pk[i] >> 32) : 0;
    s[t] = v;
    __syncthreads();
    for (int off = 1; off < 512; off <<= 1) {
        int u = (t >= off) ? s[t - off] : 0;
        __syncthreads();
        s[t] += u;
        __syncthreads();
    }
    if (i < L) ptr[i] = bsum[blockIdx.x] + s[t] - v;
    if (i == 0) ptr[L] = total;
}

// place each edge in both CSR segments at ptr[dst] + captured rank — NO atomics
__global__ void fill_ranked_kernel(const int* __restrict__ row, const int* __restrict__ col,
                                   const float* __restrict__ w,
                                   const float* __restrict__ dinv,
                                   const u8* __restrict__ rank_f, const u8* __restrict__ rank_b,
                                   const int* __restrict__ ptr,
                                   float2* __restrict__ edata,
                                   int N, int E) {
    int e = blockIdx.x * blockDim.x + threadIdx.x;
    if (e >= E) return;
    int r = row[e], c = col[e];
    float wn = w[e] * dinv[r] * dinv[N + c];
    int p1 = ptr[r] + rank_f[e];         // fwd: dst=r, src=c
    edata[p1] = make_float2(__int_as_float(c), wn);
    int p2 = ptr[N + c] + rank_b[e];     // bwd: dst=c, src=r
    edata[p2] = make_float2(__int_as_float(r), wn);
}

// fused: y1 = bf16(ALPHA * x @ Ws^T), y2 = bf16((1-ALPHA) * x @ Wd^T), one pass over x
__global__ void transform2_kernel(const float* __restrict__ x,
                                  const float* __restrict__ Ws, const float* __restrict__ Wd,
                                  u16* __restrict__ y1, u16* __restrict__ y2, int N) {
    __shared__ float xs[64][65];
    __shared__ float Wt1[64][68];
    __shared__ float Wt2[64][68];
    int t = threadIdx.x;
    for (int i = t; i < 4096; i += 256) {
        int o = i >> 6, k = i & 63;
        Wt1[k][o] = Ws[i];
        Wt2[k][o] = Wd[i];
    }
    int r0 = blockIdx.x * 64;
    for (int i = t; i < 4096; i += 256) {
        int r = i >> 6, k = i & 63;
        int gr = r0 + r;
        xs[r][k] = (gr < N) ? x[(size_t)gr * D + k] : 0.f;
    }
    __syncthreads();
    int ro = t >> 4, co = t & 15;
    float a1[4][4] = {}, a2[4][4] = {};
#pragma unroll 4
    for (int k = 0; k < 64; ++k) {
        float v0 = xs[ro * 4 + 0][k];
        float v1 = xs[ro * 4 + 1][k];
        float v2 = xs[ro * 4 + 2][k];
        float v3 = xs[ro * 4 + 3][k];
        float4 b1 = *(const float4*)&Wt1[k][co * 4];
        float4 b2 = *(const float4*)&Wt2[k][co * 4];
        a1[0][0] += v0 * b1.x; a1[0][1] += v0 * b1.y; a1[0][2] += v0 * b1.z; a1[0][3] += v0 * b1.w;
        a1[1][0] += v1 * b1.x; a1[1][1] += v1 * b1.y; a1[1][2] += v1 * b1.z; a1[1][3] += v1 * b1.w;
        a1[2][0] += v2 * b1.x; a1[2][1] += v2 * b1.y; a1[2][2] += v2 * b1.z; a1[2][3] += v2 * b1.w;
        a1[3][0] += v3 * b1.x; a1[3][1] += v3 * b1.y; a1[3][2] += v3 * b1.z; a1[3][3] += v3 * b1.w;
        a2[0][0] += v0 * b2.x; a2[0][1] += v0 * b2.y; a2[0][2] += v0 * b2.z; a2[0][3] += v0 * b2.w;
        a2[1][0] += v1 * b2.x; a2[1][1] += v1 * b2.y; a2[1][2] += v1 * b2.z; a2[1][3] += v1 * b2.w;
        a2[2][0] += v2 * b2.x; a2[2][1] += v2 * b2.y; a2[2][2] += v2 * b2.z; a2[2][3] += v2 * b2.w;
        a2[3][0] += v3 * b2.x; a2[3][1] += v3 * b2.y; a2[3][2] += v3 * b2.z; a2[3][3] += v3 * b2.w;
    }
#pragma unroll
    for (int i = 0; i < 4; ++i) {
        int gr = r0 + ro * 4 + i;
        if (gr < N) {
            ushort4 o1, o2;
            o1.x = f2bf(a1[i][0] * ALPHA); o1.y = f2bf(a1[i][1] * ALPHA);
            o1.z = f2bf(a1[i][2] * ALPHA); o1.w = f2bf(a1[i][3] * ALPHA);
            o2.x = f2bf(a2[i][0] * (1.f - ALPHA)); o2.y = f2bf(a2[i][1] * (1.f - ALPHA));
            o2.z = f2bf(a2[i][2] * (1.f - ALPHA)); o2.w = f2bf(a2[i][3] * (1.f - ALPHA));
            *(ushort4*)&y1[(size_t)gr * D + co * 4] = o1;
            *(ushort4*)&y2[(size_t)gr * D + co * 4] = o2;
        }
    }
}

// one wave per node; 64 lanes = 4 edge-slots (g) x 16 feature-slots (fl).
// One y-load instruction fetches 4 full bf16 rows (4 x 128B); one edata load
// covers up to 8 edges (64B). 2 independent chains per iteration for MLP.
__global__ void gather_merged_kernel(const int* __restrict__ ptr, const float2* __restrict__ ed,
                                     const u16* __restrict__ y1, const u16* __restrict__ y2,
                                     const float* __restrict__ b_src, const float* __restrict__ b_dst,
                                     float* __restrict__ out, int N) {
    int tid = threadIdx.x;
    int lane = tid & 63;
    int node = blockIdx.x * (blockDim.x >> 6) + (tid >> 6);
    if (node >= N) return;
    int g  = lane >> 4;      // edge slot within group of 4
    int fl = lane & 15;      // feature slot: features 4*fl .. 4*fl+3
    float a0 = 0.f, a1 = 0.f, a2 = 0.f, a3 = 0.f;

#pragma unroll
    for (int dir = 0; dir < 2; ++dir) {
        const u16* __restrict__ y = dir ? y2 : y1;
        int e0 = ptr[dir ? (N + node) : node];
        int e1 = ptr[(dir ? (N + node) : node) + 1];
        for (int eb = e0; eb < e1; eb += 8) {
            int ea = eb + g, ebx = eb + 4 + g;
            float2 da = (ea  < e1) ? ed[ea]  : make_float2(__int_as_float(0), 0.f);
            float2 db = (ebx < e1) ? ed[ebx] : make_float2(__int_as_float(0), 0.f);
            int sa = __float_as_int(da.x), sb = __float_as_int(db.x);
            float wa = da.y, wb = db.y;
            u64 qa = *(const u64*)(y + (((size_t)sa) << 6) + (fl << 2));
            u64 qb = *(const u64*)(y + (((size_t)sb) << 6) + (fl << 2));
            a0 += wa * bf2f((u16)(qa));
            a1 += wa * bf2f((u16)(qa >> 16));
            a2 += wa * bf2f((u16)(qa >> 32));
            a3 += wa * bf2f((u16)(qa >> 48));
            a0 += wb * bf2f((u16)(qb));
            a1 += wb * bf2f((u16)(qb >> 16));
            a2 += wb * bf2f((u16)(qb >> 32));
            a3 += wb * bf2f((u16)(qb >> 48));
        }
    }
    // combine the 4 edge groups: lanes l, l^16, l^32 share the same fl
    a0 += __shfl_xor(a0, 16); a0 += __shfl_xor(a0, 32);
    a1 += __shfl_xor(a1, 16); a1 += __shfl_xor(a1, 32);
    a2 += __shfl_xor(a2, 16); a2 += __shfl_xor(a2, 32);
    a3 += __shfl_xor(a3, 16); a3 += __shfl_xor(a3, 32);
    if (g == 0) {
        float4 bs = *(const float4*)&b_src[fl << 2];
        float4 bd = *(const float4*)&b_dst[fl << 2];
        f32x4 o;
        o.x = a0 + ALPHA * bs.x + (1.f - ALPHA) * bd.x;
        o.y = a1 + ALPHA * bs.y + (1.f - ALPHA) * bd.y;
        o.z = a2 + ALPHA * bs.z + (1.f - ALPHA) * bd.z;
        o.w = a3 + ALPHA * bs.w + (1.f - ALPHA) * bd.w;
        __builtin_nontemporal_store(o, (f32x4*)&out[((size_t)node << 6) + (fl << 2)]);
    }
}

extern "C" void kernel_launch(void* const* d_in, const int* in_sizes, int n_in,
                              void* d_out, int out_size, void* d_ws, size_t ws_size,
                              hipStream_t stream) {
    const float* x     = (const float*)d_in[0];
    const int*   ei    = (const int*)d_in[1];
    const float* w     = (const float*)d_in[2];
    const float* W_src = (const float*)d_in[3];
    const float* b_src = (const float*)d_in[4];
    const float* W_dst = (const float*)d_in[5];
    const float* b_dst = (const float*)d_in[6];
    float* out = (float*)d_out;

    const int N = in_sizes[0] / D;
    const int E = in_sizes[2];
    const int* row = ei;
    const int* col = ei + E;
    const int L = 2 * N;
    const int NB = (L + 511) / 512;    // 391 for N=100k, fits scan2's 512

    // workspace layout (16B-aligned chunks), ~57 MB total
    char* base = (char*)d_ws;
    size_t off = 0;
    auto take = [&](size_t bytes) { char* p = base + off; off = (off + bytes + 15) & ~(size_t)15; return p; };
    u64*    pk     = (u64*)take((size_t)L * 8);
    float*  dinv   = (float*)take((size_t)L * 4);
    int*    ptr    = (int*)take((size_t)(L + 1) * 4);
    int*    bsum   = (int*)take(512 * 4);
    u8*     rank_f = (u8*)take((size_t)E);
    u8*     rank_b = (u8*)take((size_t)E);
    u16*    y1     = (u16*)take((size_t)N * D * 2);
    u16*    y2     = (u16*)take((size_t)N * D * 2);
    float2* edata  = (float2*)take((size_t)2 * E * 8);

    // 1. zero packed degree/count array (2N u64 = N int4)
    zero4_kernel<<<(N + 255) / 256, 256, 0, stream>>>((int4*)pk, N);
    // 2. packed degrees + histogram, capturing per-edge ranks from atomic returns
    deg_hist_rank_kernel<<<2048, 256, 0, stream>>>(row, col, w, pk, rank_f, rank_b, N, E);
    // 3. d^-1/2
    unpack_kernel<<<(L + 255) / 256, 256, 0, stream>>>(pk, dinv, L);
    // 4. exclusive scan of counts -> ptr
    scan1_kernel<<<NB, 512, 0, stream>>>(pk, bsum, L);
    scan2_kernel<<<1, 512, 0, stream>>>(bsum, NB);
    scan3_kernel<<<NB, 512, 0, stream>>>(pk, bsum, ptr, L, 2 * E);
    // 5. fill CSR edge lists via ptr+rank (atomic-free)
    fill_ranked_kernel<<<(E + 255) / 256, 256, 0, stream>>>(row, col, w, dinv, rank_f, rank_b,
                                                            ptr, edata, N, E);
    // 6. both transforms in one pass (bf16 outputs), then one merged gather
    transform2_kernel<<<(N + 63) / 64, 256, 0, stream>>>(x, W_src, W_dst, y1, y2, N);
    gather_merged_kernel<<<(N + 3) / 4, 256, 0, stream>>>(ptr, edata, y1, y2,
                                                          b_src, b_dst, out, N);
}

// Round 8
// 330.680 us; speedup vs baseline: 1.4507x; 1.1093x over previous
//
#include <hip/hip_runtime.h>

#define D 64
#define ALPHA 0.5f
#define FXSCALE 16777216.f   // 2^24 fixed-point quantum for degree accumulation

typedef unsigned long long u64;
typedef unsigned char u8;
typedef unsigned short u16;
typedef float f32x4 __attribute__((ext_vector_type(4)));   // NT-store-compatible vector

// float -> bf16 (round to nearest even), as ushort
static __device__ __forceinline__ u16 f2bf(float f) {
    unsigned u = __float_as_uint(f);
    unsigned r = (u + 0x7fffu + ((u >> 16) & 1u)) >> 16;
    return (u16)r;
}
// bf16 (ushort) -> float: exact
static __device__ __forceinline__ float bf2f(u16 h) {
    return __uint_as_float(((unsigned)h) << 16);
}

__global__ void zero4_kernel(int4* __restrict__ p, int n4) {
    int i = blockIdx.x * blockDim.x + threadIdx.x;
    if (i < n4) p[i] = make_int4(0, 0, 0, 0);
}

// Heterogeneous kernel: deg-histogram blocks + transform tiles co-resident.
// deg blocks: one packed 64-bit atomic per (edge, side): hi32=count, lo32=sum(w*2^24);
//             atomic return captures the edge's rank in its destination segment.
// transform blocks: y1 = bf16(ALPHA * x @ Ws^T), y2 = bf16((1-ALPHA) * x @ Wd^T).
// The transform (VALU + coalesced reads) hides inside the deg pass's atomic
// shadow (deg is backend-bound: VALUBusy ~0.5%, ~700 GB/s write-through).
__global__ void fused_deg_transform_kernel(
        const int* __restrict__ row, const int* __restrict__ col,
        const float* __restrict__ w,
        u64* __restrict__ pk, u8* __restrict__ rank_f, u8* __restrict__ rank_b,
        const float* __restrict__ x,
        const float* __restrict__ Ws, const float* __restrict__ Wd,
        u16* __restrict__ y1, u16* __restrict__ y2,
        int N, int E, int t_count, int d_count, int total_blocks) {
    int b = blockIdx.x;
    // Bresenham spread: exactly t_count transform blocks, evenly interleaved
    int t_before = (int)(((long long)b * t_count) / total_blocks);
    bool is_t = (int)(((long long)(b + 1) * t_count) / total_blocks) > t_before;

    if (!is_t) {
        // ---- degree/histogram/rank role ----
        int d_idx = b - t_before;
        int stride = d_count * blockDim.x;
        for (int e = d_idx * blockDim.x + threadIdx.x; e < E; e += stride) {
            int r = row[e], c = col[e];
            u64 v = (1ULL << 32) | (u64)__float2uint_rn(w[e] * FXSCALE);
            u64 o1 = atomicAdd(&pk[r], v);
            rank_f[e] = (u8)(o1 >> 32);
            u64 o2 = atomicAdd(&pk[N + c], v);
            rank_b[e] = (u8)(o2 >> 32);
        }
        return;
    }

    // ---- transform role: 64-row tile, 256 threads, 4x4x2 outputs/thread ----
    __shared__ float xs[64][65];
    __shared__ float Wt1[64][65];   // pad 65: stride%32==1 -> conflict-free staging
    __shared__ float Wt2[64][65];
    int t = threadIdx.x;
    for (int i = t; i < 4096; i += 256) {
        int o = i >> 6, k = i & 63;
        Wt1[k][o] = Ws[i];
        Wt2[k][o] = Wd[i];
    }
    int r0 = t_before * 64;
    for (int i = t; i < 4096; i += 256) {
        int r = i >> 6, k = i & 63;
        int gr = r0 + r;
        xs[r][k] = (gr < N) ? x[(size_t)gr * D + k] : 0.f;
    }
    __syncthreads();
    int ro = t >> 4, co = t & 15;
    float a1[4][4] = {}, a2[4][4] = {};
#pragma unroll 4
    for (int k = 0; k < 64; ++k) {
        float v0 = xs[ro * 4 + 0][k];
        float v1 = xs[ro * 4 + 1][k];
        float v2 = xs[ro * 4 + 2][k];
        float v3 = xs[ro * 4 + 3][k];
        float4 b1 = *(const float4*)&Wt1[k][co * 4];
        float4 b2 = *(const float4*)&Wt2[k][co * 4];
        a1[0][0] += v0 * b1.x; a1[0][1] += v0 * b1.y; a1[0][2] += v0 * b1.z; a1[0][3] += v0 * b1.w;
        a1[1][0] += v1 * b1.x; a1[1][1] += v1 * b1.y; a1[1][2] += v1 * b1.z; a1[1][3] += v1 * b1.w;
        a1[2][0] += v2 * b1.x; a1[2][1] += v2 * b1.y; a1[2][2] += v2 * b1.z; a1[2][3] += v2 * b1.w;
        a1[3][0] += v3 * b1.x; a1[3][1] += v3 * b1.y; a1[3][2] += v3 * b1.z; a1[3][3] += v3 * b1.w;
        a2[0][0] += v0 * b2.x; a2[0][1] += v0 * b2.y; a2[0][2] += v0 * b2.z; a2[0][3] += v0 * b2.w;
        a2[1][0] += v1 * b2.x; a2[1][1] += v1 * b2.y; a2[1][2] += v1 * b2.z; a2[1][3] += v1 * b2.w;
        a2[2][0] += v2 * b2.x; a2[2][1] += v2 * b2.y; a2[2][2] += v2 * b2.z; a2[2][3] += v2 * b2.w;
        a2[3][0] += v3 * b2.x; a2[3][1] += v3 * b2.y; a2[3][2] += v3 * b2.z; a2[3][3] += v3 * b2.w;
    }
#pragma unroll
    for (int i = 0; i < 4; ++i) {
        int gr = r0 + ro * 4 + i;
        if (gr < N) {
            ushort4 o1, o2;
            o1.x = f2bf(a1[i][0] * ALPHA); o1.y = f2bf(a1[i][1] * ALPHA);
            o1.z = f2bf(a1[i][2] * ALPHA); o1.w = f2bf(a1[i][3] * ALPHA);
            o2.x = f2bf(a2[i][0] * (1.f - ALPHA)); o2.y = f2bf(a2[i][1] * (1.f - ALPHA));
            o2.z = f2bf(a2[i][2] * (1.f - ALPHA)); o2.w = f2bf(a2[i][3] * (1.f - ALPHA));
            *(ushort4*)&y1[(size_t)gr * D + co * 4] = o1;
            *(ushort4*)&y2[(size_t)gr * D + co * 4] = o2;
        }
    }
}

// ---- scan over counts (pk >> 32) -> ptr[0..L]; scan1 also emits dinv ----
__global__ void scan1_unpack_kernel(const u64* __restrict__ pk, int* __restrict__ bsum,
                                    float* __restrict__ dinv, int L) {
    __shared__ int s[512];
    int t = threadIdx.x;
    int i = blockIdx.x * 512 + t;
    u64 p = (i < L) ? pk[i] : 0ULL;
    // fused unpack: dinv[i] = deg^-1/2 (0 if empty)
    if (i < L) {
        float sum = (float)(unsigned int)(p & 0xffffffffULL) * (1.f / FXSCALE);
        dinv[i] = (sum > 0.f) ? rsqrtf(sum) : 0.f;
    }
    s[t] = (int)(p >> 32);
    __syncthreads();
    for (int off = 256; off; off >>= 1) {
        if (t < off) s[t] += s[t + off];
        __syncthreads();
    }
    if (t == 0) bsum[blockIdx.x] = s[0];
}

__global__ void scan2_kernel(int* __restrict__ bsum, int nb) {
    __shared__ int s[512];
    int t = threadIdx.x;
    int v = (t < nb) ? bsum[t] : 0;
    s[t] = v;
    __syncthreads();
    for (int off = 1; off < 512; off <<= 1) {
        int u = (t >= off) ? s[t - off] : 0;
        __syncthreads();
        s[t] += u;
        __syncthreads();
    }
    if (t < nb) bsum[t] = s[t] - v;   // exclusive block offsets
}

__global__ void scan3_kernel(const u64* __restrict__ pk, const int* __restrict__ bsum,
                             int* __restrict__ ptr, int L, int total) {
    __shared__ int s[512];
    int t = threadIdx.x;
    int i = blockIdx.x * 512 + t;
    int v = (i < L) ? (int)(pk[i] >> 32) : 0;
    s[t] = v;
    __syncthreads();
    for (int off = 1; off < 512; off <<= 1) {
        int u = (t >= off) ? s[t - off] : 0;
        __syncthreads();
        s[t] += u;
        __syncthreads();
    }
    if (i < L) ptr[i] = bsum[blockIdx.x] + s[t] - v;
    if (i == 0) ptr[L] = total;
}

// place each edge in both CSR segments at ptr[dst] + captured rank — NO atomics
__global__ void fill_ranked_kernel(const int* __restrict__ row, const int* __restrict__ col,
                                   const float* __restrict__ w,
                                   const float* __restrict__ dinv,
                                   const u8* __restrict__ rank_f, const u8* __restrict__ rank_b,
                                   const int* __restrict__ ptr,
                                   float2* __restrict__ edata,
                                   int N, int E) {
    int e = blockIdx.x * blockDim.x + threadIdx.x;
    if (e >= E) return;
    int r = row[e], c = col[e];
    float wn = w[e] * dinv[r] * dinv[N + c];
    int p1 = ptr[r] + rank_f[e];         // fwd: dst=r, src=c
    edata[p1] = make_float2(__int_as_float(c), wn);
    int p2 = ptr[N + c] + rank_b[e];     // bwd: dst=c, src=r
    edata[p2] = make_float2(__int_as_float(r), wn);
}

// one wave per node; 64 lanes = 4 edge-slots (g) x 16 feature-slots (fl).
// One y-load instruction fetches 4 full bf16 rows (4 x 128B); one edata load
// covers up to 8 edges (64B). 2 independent chains per iteration for MLP.
__global__ void gather_merged_kernel(const int* __restrict__ ptr, const float2* __restrict__ ed,
                                     const u16* __restrict__ y1, const u16* __restrict__ y2,
                                     const float* __restrict__ b_src, const float* __restrict__ b_dst,
                                     float* __restrict__ out, int N) {
    int tid = threadIdx.x;
    int lane = tid & 63;
    int node = blockIdx.x * (blockDim.x >> 6) + (tid >> 6);
    if (node >= N) return;
    int g  = lane >> 4;      // edge slot within group of 4
    int fl = lane & 15;      // feature slot: features 4*fl .. 4*fl+3
    float a0 = 0.f, a1 = 0.f, a2 = 0.f, a3 = 0.f;

#pragma unroll
    for (int dir = 0; dir < 2; ++dir) {
        const u16* __restrict__ y = dir ? y2 : y1;
        int e0 = ptr[dir ? (N + node) : node];
        int e1 = ptr[(dir ? (N + node) : node) + 1];
        for (int eb = e0; eb < e1; eb += 8) {
            int ea = eb + g, ebx = eb + 4 + g;
            float2 da = (ea  < e1) ? ed[ea]  : make_float2(__int_as_float(0), 0.f);
            float2 db = (ebx < e1) ? ed[ebx] : make_float2(__int_as_float(0), 0.f);
            int sa = __float_as_int(da.x), sb = __float_as_int(db.x);
            float wa = da.y, wb = db.y;
            u64 qa = *(const u64*)(y + (((size_t)sa) << 6) + (fl << 2));
            u64 qb = *(const u64*)(y + (((size_t)sb) << 6) + (fl << 2));
            a0 += wa * bf2f((u16)(qa));
            a1 += wa * bf2f((u16)(qa >> 16));
            a2 += wa * bf2f((u16)(qa >> 32));
            a3 += wa * bf2f((u16)(qa >> 48));
            a0 += wb * bf2f((u16)(qb));
            a1 += wb * bf2f((u16)(qb >> 16));
            a2 += wb * bf2f((u16)(qb >> 32));
            a3 += wb * bf2f((u16)(qb >> 48));
        }
    }
    // combine the 4 edge groups: lanes l, l^16, l^32 share the same fl
    a0 += __shfl_xor(a0, 16); a0 += __shfl_xor(a0, 32);
    a1 += __shfl_xor(a1, 16); a1 += __shfl_xor(a1, 32);
    a2 += __shfl_xor(a2, 16); a2 += __shfl_xor(a2, 32);
    a3 += __shfl_xor(a3, 16); a3 += __shfl_xor(a3, 32);
    if (g == 0) {
        float4 bs = *(const float4*)&b_src[fl << 2];
        float4 bd = *(const float4*)&b_dst[fl << 2];
        f32x4 o;
        o.x = a0 + ALPHA * bs.x + (1.f - ALPHA) * bd.x;
        o.y = a1 + ALPHA * bs.y + (1.f - ALPHA) * bd.y;
        o.z = a2 + ALPHA * bs.z + (1.f - ALPHA) * bd.z;
        o.w = a3 + ALPHA * bs.w + (1.f - ALPHA) * bd.w;
        __builtin_nontemporal_store(o, (f32x4*)&out[((size_t)node << 6) + (fl << 2)]);
    }
}

extern "C" void kernel_launch(void* const* d_in, const int* in_sizes, int n_in,
                              void* d_out, int out_size, void* d_ws, size_t ws_size,
                              hipStream_t stream) {
    const float* x     = (const float*)d_in[0];
    const int*   ei    = (const int*)d_in[1];
    const float* w     = (const float*)d_in[2];
    const float* W_src = (const float*)d_in[3];
    const float* b_src = (const float*)d_in[4];
    const float* W_dst = (const float*)d_in[5];
    const float* b_dst = (const float*)d_in[6];
    float* out = (float*)d_out;

    const int N = in_sizes[0] / D;
    const int E = in_sizes[2];
    const int* row = ei;
    const int* col = ei + E;
    const int L = 2 * N;
    const int NB = (L + 511) / 512;    // 391 for N=100k, fits scan2's 512

    // workspace layout (16B-aligned chunks), ~57 MB total
    char* base = (char*)d_ws;
    size_t off = 0;
    auto take = [&](size_t bytes) { char* p = base + off; off = (off + bytes + 15) & ~(size_t)15; return p; };
    u64*    pk     = (u64*)take((size_t)L * 8);
    float*  dinv   = (float*)take((size_t)L * 4);
    int*    ptr    = (int*)take((size_t)(L + 1) * 4);
    int*    bsum   = (int*)take(512 * 4);
    u8*     rank_f = (u8*)take((size_t)E);
    u8*     rank_b = (u8*)take((size_t)E);
    u16*    y1     = (u16*)take((size_t)N * D * 2);
    u16*    y2     = (u16*)take((size_t)N * D * 2);
    float2* edata  = (float2*)take((size_t)2 * E * 8);

    const int t_count = (N + 63) / 64;          // transform tiles (1563)
    const int d_count = 2048;                   // deg blocks
    const int total_blocks = t_count + d_count;

    // 1. zero packed degree/count array (2N u64 = N int4)
    zero4_kernel<<<(N + 255) / 256, 256, 0, stream>>>((int4*)pk, N);
    // 2. fused: packed degrees + histogram + rank capture, with transform tiles
    //    interleaved to hide in the atomic shadow
    fused_deg_transform_kernel<<<total_blocks, 256, 0, stream>>>(
        row, col, w, pk, rank_f, rank_b, x, W_src, W_dst, y1, y2,
        N, E, t_count, d_count, total_blocks);
    // 3. scan counts -> ptr (scan1 also unpacks dinv)
    scan1_unpack_kernel<<<NB, 512, 0, stream>>>(pk, bsum, dinv, L);
    scan2_kernel<<<1, 512, 0, stream>>>(bsum, NB);
    scan3_kernel<<<NB, 512, 0, stream>>>(pk, bsum, ptr, L, 2 * E);
    // 4. fill CSR edge lists via ptr+rank (atomic-free)
    fill_ranked_kernel<<<(E + 255) / 256, 256, 0, stream>>>(row, col, w, dinv, rank_f, rank_b,
                                                            ptr, edata, N, E);
    // 5. merged gather (single out write)
    gather_merged_kernel<<<(N + 3) / 4, 256, 0, stream>>>(ptr, edata, y1, y2,
                                                          b_src, b_dst, out, N);
}